// Round 4
// baseline (506.558 us; speedup 1.0000x reference)
//
#include <hip/hip_runtime.h>
#include <hip/hip_bf16.h>

#define B_ 8
#define N_ 4096
#define D_ 512
#define K_ 64
#define QD_ 128

__device__ __forceinline__ void load8f(const float* p, float* r) {
  float4 a = *(const float4*)(p);
  float4 b = *(const float4*)(p + 4);
  r[0] = a.x; r[1] = a.y; r[2] = a.z; r[3] = a.w;
  r[4] = b.x; r[5] = b.y; r[6] = b.z; r[7] = b.w;
}

// ---------------------------------------------------------------------------
// K1: segment-sum scatter. grid (16 chunks, 4 d-quarters, 8 batches) x 128.
// Thread t owns column d = dq*128 + t of all 64 bins -> race-free LDS adds.
// ---------------------------------------------------------------------------
__global__ __launch_bounds__(128) void k_scatter(
    const float* __restrict__ q, const int* __restrict__ aidx,
    const float* __restrict__ aw, const float* __restrict__ mask,
    float* __restrict__ proto_raw, float* __restrict__ wsum) {
  __shared__ float acc[K_ * 128];
  __shared__ float wsh[K_];
  const int t = threadIdx.x;
  const int chunk = blockIdx.x;   // 0..15
  const int dq = blockIdx.y;      // 0..3
  const int b = blockIdx.z;       // 0..7
  for (int i = t; i < K_ * 128; i += 128) acc[i] = 0.f;
  if (t < K_) wsh[t] = 0.f;
  __syncthreads();
  const int rows = N_ / 16;  // 256
  const int n0 = chunk * rows;
  for (int r = 0; r < rows; ++r) {
    const size_t gr = (size_t)b * N_ + (n0 + r);
    const float qv = q[gr * D_ + dq * 128 + t];
    const float mk = mask[gr];
    const size_t ib = gr * 3;
    const int k0 = aidx[ib], k1 = aidx[ib + 1], k2 = aidx[ib + 2];
    const float w0 = aw[ib] * mk, w1 = aw[ib + 1] * mk, w2 = aw[ib + 2] * mk;
    acc[k0 * 128 + t] += qv * w0;
    acc[k1 * 128 + t] += qv * w1;
    acc[k2 * 128 + t] += qv * w2;
    if (dq == 0 && t == 0) { wsh[k0] += w0; wsh[k1] += w1; wsh[k2] += w2; }
  }
  __syncthreads();
  for (int i = t; i < K_ * 128; i += 128) {
    const int k = i >> 7;  // i % 128 == t
    atomicAdd(&proto_raw[(size_t)(b * K_ + k) * D_ + dq * 128 + t], acc[i]);
  }
  if (dq == 0 && t < K_) atomicAdd(&wsum[b * K_ + t], wsh[t]);
}

// ---------------------------------------------------------------------------
// K2: proto normalize + quaternion_linear(proto_w) -> proto_t (f32, ws) and
// proto output (f32, d_out).
// ---------------------------------------------------------------------------
__global__ __launch_bounds__(128) void k_proto(
    const float* __restrict__ proto_raw, const float* __restrict__ wsum,
    const float* __restrict__ pw, const float* __restrict__ pb,
    float* __restrict__ proto_t, float* __restrict__ out_proto) {
  __shared__ float x[8][D_];
  __shared__ float inv[8];
  const int t = threadIdx.x;  // 128
  const int row0 = blockIdx.x * 8;
  if (t < 8) inv[t] = 1.f / (wsum[row0 + t] + 1e-6f);
  __syncthreads();
  for (int r = 0; r < 8; ++r)
    for (int v = t; v < D_; v += 128)
      x[r][v] = proto_raw[(size_t)(row0 + r) * D_ + v] * inv[r];
  __syncthreads();

  const int   matT[4][4] = {{0,1,2,3},{1,0,3,2},{2,3,0,1},{3,2,1,0}};
  const float sgnT[4][4] = {{1.f,-1.f,-1.f,-1.f},{1.f,1.f,-1.f,1.f},
                            {1.f,1.f,1.f,-1.f},{1.f,-1.f,1.f,1.f}};
  float accu[4][8];
#pragma unroll
  for (int u = 0; u < 4; ++u) {
    const float bias = pb[u * 128 + t];
#pragma unroll
    for (int r = 0; r < 8; ++r) accu[u][r] = bias;
  }
#pragma unroll
  for (int u = 0; u < 4; ++u) {
#pragma unroll
    for (int c = 0; c < 4; ++c) {
      const float* wr = pw + matT[u][c] * QD_ * QD_ + t * QD_;
      const float s = sgnT[u][c];
#pragma unroll 4
      for (int bb = 0; bb < QD_; ++bb) {
        const float wv = s * wr[bb];
#pragma unroll
        for (int r = 0; r < 8; ++r) accu[u][r] += wv * x[r][c * 128 + bb];
      }
    }
  }
#pragma unroll
  for (int u = 0; u < 4; ++u)
    for (int r = 0; r < 8; ++r) {
      const size_t o = (size_t)(row0 + r) * D_ + u * 128 + t;
      proto_t[o] = accu[u][r];
      out_proto[o] = accu[u][r];
    }
}

// ---------------------------------------------------------------------------
// K2b: expand upd quaternion weights into dense f32 W^T: wt[v][o] = W[o][v]
// ---------------------------------------------------------------------------
__global__ __launch_bounds__(256) void k_wt(const float* __restrict__ uw,
                                            float* __restrict__ wt) {
  const int idx = blockIdx.x * 256 + threadIdx.x;  // < 512*512, idx = v*512+o
  const int v = idx >> 9, o = idx & 511;
  const int u = o >> 7, a = o & 127, c = v >> 7, bb = v & 127;
  const int   matT[4][4] = {{0,1,2,3},{1,0,3,2},{2,3,0,1},{3,2,1,0}};
  const float sgnT[4][4] = {{1.f,-1.f,-1.f,-1.f},{1.f,1.f,-1.f,1.f},
                            {1.f,1.f,1.f,-1.f},{1.f,-1.f,1.f,1.f}};
  wt[idx] = sgnT[u][c] * uw[matT[u][c] * QD_ * QD_ + a * QD_ + bb];
}

// ---------------------------------------------------------------------------
// K3: fused routing + hamilton + upd linear (f32 VALU) + residual + quat-LN.
// grid 2048 x 256 threads; 16 rows per block; thread owns 2 output columns.
// Wave w (64 lanes) owns columns [w*128, w*128+128) == quaternion component w.
// ---------------------------------------------------------------------------
__global__ __launch_bounds__(256) void k_main2(
    const float* __restrict__ q, const int* __restrict__ aidx,
    const float* __restrict__ aw, const float* __restrict__ proto_t,
    const float* __restrict__ wt, const float* __restrict__ ub,
    const float* __restrict__ gamma, const float* __restrict__ beta,
    float* __restrict__ out_q) {
  __shared__ float msgF[16 * 512];
  const int t = threadIdx.x;
  const size_t R0 = (size_t)blockIdx.x * 16;

  // ---- stage A: msg rows -> LDS (f32, plain layout) ----
  {
    const int s = t & 15;    // channel group of 8
    const int row = t >> 4;  // 0..15
    const size_t gr = R0 + row;
    const int b = (int)(gr >> 12);
    const float* qp = q + gr * D_ + s * 8;
    float qr_[8], qi_[8], qj_[8], qk_[8];
    load8f(qp, qr_); load8f(qp + 128, qi_);
    load8f(qp + 256, qj_); load8f(qp + 384, qk_);
    float mr[8], mi[8], mj[8], mk[8];
#pragma unroll
    for (int e = 0; e < 8; ++e) { mr[e] = mi[e] = mj[e] = mk[e] = 0.f; }
    for (int j = 0; j < 3; ++j) {
      const int kk = aidx[gr * 3 + j];
      const float w = aw[gr * 3 + j];  // raw assign_w (mask==1 anyway)
      const float* pp = proto_t + (size_t)(b * K_ + kk) * D_ + s * 8;
      float pr[8], pi[8], pj[8], pk[8];
      load8f(pp, pr); load8f(pp + 128, pi);
      load8f(pp + 256, pj); load8f(pp + 384, pk);
#pragma unroll
      for (int e = 0; e < 8; ++e) {
        mr[e] += w * (qr_[e]*pr[e] - qi_[e]*pi[e] - qj_[e]*pj[e] - qk_[e]*pk[e]);
        mi[e] += w * (qr_[e]*pi[e] + qi_[e]*pr[e] + qj_[e]*pk[e] - qk_[e]*pj[e]);
        mj[e] += w * (qr_[e]*pj[e] - qi_[e]*pk[e] + qj_[e]*pr[e] + qk_[e]*pi[e]);
        mk[e] += w * (qr_[e]*pk[e] + qi_[e]*pj[e] - qj_[e]*pi[e] + qk_[e]*pr[e]);
      }
    }
    const float* srcs[4] = {mr, mi, mj, mk};
#pragma unroll
    for (int u = 0; u < 4; ++u) {
      const float* m = srcs[u];
      float4 lo; lo.x = m[0]; lo.y = m[1]; lo.z = m[2]; lo.w = m[3];
      float4 hi; hi.x = m[4]; hi.y = m[5]; hi.z = m[6]; hi.w = m[7];
      float* dst = msgF + row * 512 + u * 128 + s * 8;
      *(float4*)(dst) = lo;
      *(float4*)(dst + 4) = hi;
    }
  }
  __syncthreads();

  // ---- stage B: out[r][c0..c0+1] = sum_v msg[r][v] * W[c][v] ----
  const int c0 = t * 2;
  float a0[16], a1[16];
  {
    const float ub0 = ub[c0], ub1 = ub[c0 + 1];
#pragma unroll
    for (int r = 0; r < 16; ++r) { a0[r] = ub0; a1[r] = ub1; }
  }
  for (int v = 0; v < 512; v += 4) {
    const float2 w0 = *(const float2*)(wt + (size_t)(v + 0) * 512 + c0);
    const float2 w1 = *(const float2*)(wt + (size_t)(v + 1) * 512 + c0);
    const float2 w2 = *(const float2*)(wt + (size_t)(v + 2) * 512 + c0);
    const float2 w3 = *(const float2*)(wt + (size_t)(v + 3) * 512 + c0);
#pragma unroll
    for (int r = 0; r < 16; ++r) {
      const float4 m = *(const float4*)(msgF + r * 512 + v);
      a0[r] += m.x * w0.x + m.y * w1.x + m.z * w2.x + m.w * w3.x;
      a1[r] += m.x * w0.y + m.y * w1.y + m.z * w2.y + m.w * w3.y;
    }
  }

  // ---- epilogue: bias(already) + residual + quaternion layernorm ----
  const float g0 = gamma[c0], g1 = gamma[c0 + 1];
  const float b0 = beta[c0], b1 = beta[c0 + 1];
#pragma unroll
  for (int r = 0; r < 16; ++r) {
    const size_t grow = R0 + r;
    const float2 qv = *(const float2*)(q + grow * D_ + c0);
    const float x0 = a0[r] + qv.x;
    const float x1 = a1[r] + qv.y;
    float s = x0 + x1;
    s += __shfl_xor(s, 1);  s += __shfl_xor(s, 2);  s += __shfl_xor(s, 4);
    s += __shfl_xor(s, 8);  s += __shfl_xor(s, 16); s += __shfl_xor(s, 32);
    const float mean = s * 0.0078125f;
    const float d0 = x0 - mean, d1 = x1 - mean;
    float sq = d0 * d0 + d1 * d1;
    sq += __shfl_xor(sq, 1);  sq += __shfl_xor(sq, 2);  sq += __shfl_xor(sq, 4);
    sq += __shfl_xor(sq, 8);  sq += __shfl_xor(sq, 16); sq += __shfl_xor(sq, 32);
    const float rstd = rsqrtf(sq * 0.0078125f + 1e-5f);
    float2 ov;
    ov.x = d0 * rstd * g0 + b0;
    ov.y = d1 * rstd * g1 + b1;
    *(float2*)(out_q + grow * D_ + c0) = ov;
  }
}

extern "C" void kernel_launch(void* const* d_in, const int* in_sizes, int n_in,
                              void* d_out, int out_size, void* d_ws, size_t ws_size,
                              hipStream_t stream) {
  const float* q     = (const float*)d_in[0];
  const int*   aidx  = (const int*)d_in[1];
  const float* aw    = (const float*)d_in[2];
  const float* mask  = (const float*)d_in[3];
  const float* pw    = (const float*)d_in[4];
  const float* pb    = (const float*)d_in[5];
  const float* uw    = (const float*)d_in[6];
  const float* ub    = (const float*)d_in[7];
  const float* gamma = (const float*)d_in[8];
  const float* beta  = (const float*)d_in[9];

  char* ws = (char*)d_ws;
  float* proto_raw = (float*)ws;                         // 1 MB
  float* wsum      = (float*)(ws + (1 << 20));           // 2 KB (pad to 4 KB)
  float* proto_t   = (float*)(ws + (1 << 20) + 4096);    // 1 MB
  float* wt        = (float*)(ws + 2 * (1 << 20) + 4096);// 1 MB

  float* out_q = (float*)d_out;                          // (B,N,D) f32
  float* out_proto = out_q + (size_t)B_ * N_ * D_;       // (B,K,D) f32

  hipMemsetAsync(d_ws, 0, (1 << 20) + 4096, stream);
  k_wt<<<1024, 256, 0, stream>>>(uw, wt);
  k_scatter<<<dim3(16, 4, 8), 128, 0, stream>>>(q, aidx, aw, mask, proto_raw, wsum);
  k_proto<<<64, 128, 0, stream>>>(proto_raw, wsum, pw, pb, proto_t, out_proto);
  k_main2<<<2048, 256, 0, stream>>>(q, aidx, aw, proto_t, wt, ub, gamma, beta, out_q);
}

// Round 5
// 218.906 us; speedup vs baseline: 2.3140x; 2.3140x over previous
//
#include <hip/hip_runtime.h>
#include <hip/hip_bf16.h>

#define B_ 8
#define N_ 4096
#define D_ 512
#define K_ 64
#define QD_ 128

typedef float f32x4 __attribute__((ext_vector_type(4)));
typedef short short8 __attribute__((ext_vector_type(8)));
typedef unsigned short u16;
typedef unsigned int u32;

__device__ __forceinline__ u16 f2bf(float f) {
  u32 u = __float_as_uint(f);
  return (u16)((u + 0x7fffu + ((u >> 16) & 1u)) >> 16);
}

__device__ __forceinline__ void load8f(const float* p, float* r) {
  float4 a = *(const float4*)(p);
  float4 b = *(const float4*)(p + 4);
  r[0] = a.x; r[1] = a.y; r[2] = a.z; r[3] = a.w;
  r[4] = b.x; r[5] = b.y; r[6] = b.z; r[7] = b.w;
}

// ---------------------------------------------------------------------------
// K0: expand quaternion weights (w4: 4 x Qd x Qd f32) into dense bf16
// W[o][v], o,v in [0,512). Used for both upd_w and proto_w.
// ---------------------------------------------------------------------------
__global__ __launch_bounds__(256) void k_wexp_bf(const float* __restrict__ w4,
                                                 u16* __restrict__ wexp) {
  const int idx = blockIdx.x * 256 + threadIdx.x;  // o*512 + v
  const int o = idx >> 9, v = idx & 511;
  const int u = o >> 7, a = o & 127, c = v >> 7, bb = v & 127;
  const int   matT[4][4] = {{0,1,2,3},{1,0,3,2},{2,3,0,1},{3,2,1,0}};
  const float sgnT[4][4] = {{1.f,-1.f,-1.f,-1.f},{1.f,1.f,-1.f,1.f},
                            {1.f,1.f,1.f,-1.f},{1.f,-1.f,1.f,1.f}};
  wexp[idx] = f2bf(sgnT[u][c] * w4[matT[u][c] * QD_ * QD_ + a * QD_ + bb]);
}

// ---------------------------------------------------------------------------
// K1a: weight-sum histogram. One block per batch; LDS atomics.
// ---------------------------------------------------------------------------
__global__ __launch_bounds__(256) void k_wsum(
    const int* __restrict__ aidx, const float* __restrict__ aw,
    const float* __restrict__ mask, float* __restrict__ wsum) {
  __shared__ float wsh[K_];
  const int b = blockIdx.x;
  const int t = threadIdx.x;
  if (t < K_) wsh[t] = 0.f;
  __syncthreads();
  const int total = N_ * 3;
  for (int i = t; i < total; i += 256) {
    const int n = i / 3;
    const size_t off = (size_t)b * total + i;
    const float w = aw[off] * mask[(size_t)b * N_ + n];
    atomicAdd(&wsh[aidx[off]], w);
  }
  __syncthreads();
  if (t < K_) wsum[b * K_ + t] = wsh[t];
}

// ---------------------------------------------------------------------------
// K1b: segment-sum scatter. grid (16 chunks, 4 d-quarters, 8 batches) x 128.
// Thread t owns column d = dq*128 + t of all 64 bins -> race-free LDS adds.
// ---------------------------------------------------------------------------
__global__ __launch_bounds__(128) void k_scatter(
    const float* __restrict__ q, const int* __restrict__ aidx,
    const float* __restrict__ aw, const float* __restrict__ mask,
    float* __restrict__ proto_raw) {
  __shared__ float acc[K_ * 128];
  const int t = threadIdx.x;
  const int chunk = blockIdx.x;   // 0..15
  const int dq = blockIdx.y;      // 0..3
  const int b = blockIdx.z;       // 0..7
  for (int i = t; i < K_ * 128; i += 128) acc[i] = 0.f;
  __syncthreads();
  const int rows = N_ / 16;  // 256
  const int n0 = chunk * rows;
  for (int r = 0; r < rows; ++r) {
    const size_t gr = (size_t)b * N_ + (n0 + r);
    const float qv = q[gr * D_ + dq * 128 + t];
    const float mk = mask[gr];
    const size_t ib = gr * 3;
    const int k0 = aidx[ib], k1 = aidx[ib + 1], k2 = aidx[ib + 2];
    const float w0 = aw[ib] * mk, w1 = aw[ib + 1] * mk, w2 = aw[ib + 2] * mk;
    acc[k0 * 128 + t] += qv * w0;
    acc[k1 * 128 + t] += qv * w1;
    acc[k2 * 128 + t] += qv * w2;
  }
  __syncthreads();
  for (int i = t; i < K_ * 128; i += 128) {
    const int k = i >> 7;  // i % 128 == t
    atomicAdd(&proto_raw[(size_t)(b * K_ + k) * D_ + dq * 128 + t], acc[i]);
  }
}

// ---------------------------------------------------------------------------
// K2: proto normalize + quaternion_linear via bf16 MFMA.
// 16 blocks x 256 threads. 32 proto rows/block, wave w owns cols [w*128,..).
// ---------------------------------------------------------------------------
__global__ __launch_bounds__(256) void k_proto_mfma(
    const float* __restrict__ proto_raw, const float* __restrict__ wsum,
    const u16* __restrict__ pwexp, const float* __restrict__ pb,
    float* __restrict__ proto_t, float* __restrict__ out_proto) {
  __shared__ __align__(16) u16 msgL[32 * 512];
  __shared__ float invs[32];
  const int t = threadIdx.x;
  const size_t R0 = (size_t)blockIdx.x * 32;
  if (t < 32) invs[t] = 1.f / (wsum[R0 + t] + 1e-6f);
  __syncthreads();

  // stage A: normalize -> bf16 -> swizzled LDS
  {
    const int s = t & 15, rr = t >> 4;
#pragma unroll
    for (int pass = 0; pass < 2; ++pass) {
      const int row = pass * 16 + rr;
      const float iv = invs[row];
      const float* base = proto_raw + (R0 + row) * D_;
      const int swz = (row & 7) << 4;
#pragma unroll
      for (int u = 0; u < 4; ++u) {
        float m[8];
        load8f(base + u * 128 + s * 8, m);
        uint4 val;
        val.x = (u32)f2bf(m[0]*iv) | ((u32)f2bf(m[1]*iv) << 16);
        val.y = (u32)f2bf(m[2]*iv) | ((u32)f2bf(m[3]*iv) << 16);
        val.z = (u32)f2bf(m[4]*iv) | ((u32)f2bf(m[5]*iv) << 16);
        val.w = (u32)f2bf(m[6]*iv) | ((u32)f2bf(m[7]*iv) << 16);
        const int byte = (row * 1024 + u * 256 + s * 16) ^ swz;
        *(uint4*)((char*)msgL + byte) = val;
      }
    }
  }
  __syncthreads();

  // stage B: GEMM 32x512x512
  const int lane = t & 63, wv = t >> 6;
  const int g = lane >> 4, l16 = lane & 15;
  const int colQ = wv * 128;
  f32x4 acc[2][8];
#pragma unroll
  for (int st = 0; st < 2; ++st)
#pragma unroll
    for (int f = 0; f < 8; ++f) { f32x4 z = {0.f,0.f,0.f,0.f}; acc[st][f] = z; }
#pragma unroll 4
  for (int ks = 0; ks < 16; ++ks) {
    short8 bfr[8];
#pragma unroll
    for (int f = 0; f < 8; ++f)
      bfr[f] = *(const short8*)(pwexp + (size_t)(colQ + f * 16 + l16) * D_ + ks * 32 + g * 8);
#pragma unroll
    for (int st = 0; st < 2; ++st) {
      const int arow = st * 16 + l16;
      const short8 a = *(const short8*)((const char*)msgL +
          ((arow * 1024 + ks * 64 + g * 16) ^ ((arow & 7) << 4)));
#pragma unroll
      for (int f = 0; f < 8; ++f)
        acc[st][f] = __builtin_amdgcn_mfma_f32_16x16x32_bf16(a, bfr[f], acc[st][f], 0, 0, 0);
    }
  }

  // epilogue: + bias, write proto_t (ws) and proto output
#pragma unroll
  for (int st = 0; st < 2; ++st)
#pragma unroll
    for (int f = 0; f < 8; ++f) {
      const int col = colQ + f * 16 + l16;
      const float pbv = pb[col];
#pragma unroll
      for (int rg = 0; rg < 4; ++rg) {
        const size_t row = R0 + st * 16 + g * 4 + rg;
        const float v = acc[st][f][rg] + pbv;
        proto_t[row * D_ + col] = v;
        out_proto[row * D_ + col] = v;
      }
    }
}

// ---------------------------------------------------------------------------
// K3: fused routing + hamilton + upd linear (bf16 MFMA) + residual + quat-LN.
// 1024 blocks x 256 threads; 32 rows/block; wave w owns cols [w*128, ..+128)
// = quaternion component w.
// ---------------------------------------------------------------------------
__global__ __launch_bounds__(256) void k_main3(
    const float* __restrict__ q, const int* __restrict__ aidx,
    const float* __restrict__ aw, const float* __restrict__ proto_t,
    const u16* __restrict__ wexp, const float* __restrict__ ub,
    const float* __restrict__ gamma, const float* __restrict__ beta,
    float* __restrict__ out_q) {
  __shared__ __align__(16) u16 msgL[32 * 512];
  const int t = threadIdx.x;
  const size_t R0 = (size_t)blockIdx.x * 32;

  // ---- stage A: Hamilton-weighted msg rows -> bf16 swizzled LDS ----
  {
    const int s = t & 15, rr = t >> 4;
#pragma unroll
    for (int pass = 0; pass < 2; ++pass) {
      const int row = pass * 16 + rr;
      const size_t gr = R0 + row;
      const int b = (int)(gr >> 12);
      const float* qp = q + gr * D_ + s * 8;
      float qr_[8], qi_[8], qj_[8], qk_[8];
      load8f(qp, qr_); load8f(qp + 128, qi_);
      load8f(qp + 256, qj_); load8f(qp + 384, qk_);
      float mr[8], mi[8], mj[8], mk[8];
#pragma unroll
      for (int e = 0; e < 8; ++e) { mr[e] = mi[e] = mj[e] = mk[e] = 0.f; }
      for (int j = 0; j < 3; ++j) {
        const int kk = aidx[gr * 3 + j];
        const float w = aw[gr * 3 + j];  // raw assign_w per reference
        const float* pp = proto_t + (size_t)(b * K_ + kk) * D_ + s * 8;
        float pr[8], pi[8], pj[8], pk[8];
        load8f(pp, pr); load8f(pp + 128, pi);
        load8f(pp + 256, pj); load8f(pp + 384, pk);
#pragma unroll
        for (int e = 0; e < 8; ++e) {
          mr[e] += w * (qr_[e]*pr[e] - qi_[e]*pi[e] - qj_[e]*pj[e] - qk_[e]*pk[e]);
          mi[e] += w * (qr_[e]*pi[e] + qi_[e]*pr[e] + qj_[e]*pk[e] - qk_[e]*pj[e]);
          mj[e] += w * (qr_[e]*pj[e] - qi_[e]*pk[e] + qj_[e]*pr[e] + qk_[e]*pi[e]);
          mk[e] += w * (qr_[e]*pk[e] + qi_[e]*pj[e] - qj_[e]*pi[e] + qk_[e]*pr[e]);
        }
      }
      const int swz = (row & 7) << 4;
      const float* srcs[4] = {mr, mi, mj, mk};
#pragma unroll
      for (int u = 0; u < 4; ++u) {
        const float* m = srcs[u];
        uint4 val;
        val.x = (u32)f2bf(m[0]) | ((u32)f2bf(m[1]) << 16);
        val.y = (u32)f2bf(m[2]) | ((u32)f2bf(m[3]) << 16);
        val.z = (u32)f2bf(m[4]) | ((u32)f2bf(m[5]) << 16);
        val.w = (u32)f2bf(m[6]) | ((u32)f2bf(m[7]) << 16);
        const int byte = (row * 1024 + u * 256 + s * 16) ^ swz;
        *(uint4*)((char*)msgL + byte) = val;
      }
    }
  }
  __syncthreads();

  // ---- stage B: GEMM 32x512x512 via mfma_f32_16x16x32_bf16 ----
  const int lane = t & 63, wv = t >> 6;
  const int g = lane >> 4, l16 = lane & 15;
  const int colQ = wv * 128;
  f32x4 acc[2][8];
#pragma unroll
  for (int st = 0; st < 2; ++st)
#pragma unroll
    for (int f = 0; f < 8; ++f) { f32x4 z = {0.f,0.f,0.f,0.f}; acc[st][f] = z; }
#pragma unroll 4
  for (int ks = 0; ks < 16; ++ks) {
    short8 bfr[8];
#pragma unroll
    for (int f = 0; f < 8; ++f)
      bfr[f] = *(const short8*)(wexp + (size_t)(colQ + f * 16 + l16) * D_ + ks * 32 + g * 8);
#pragma unroll
    for (int st = 0; st < 2; ++st) {
      const int arow = st * 16 + l16;
      const short8 a = *(const short8*)((const char*)msgL +
          ((arow * 1024 + ks * 64 + g * 16) ^ ((arow & 7) << 4)));
#pragma unroll
      for (int f = 0; f < 8; ++f)
        acc[st][f] = __builtin_amdgcn_mfma_f32_16x16x32_bf16(a, bfr[f], acc[st][f], 0, 0, 0);
    }
  }

  // ---- epilogue: bias + residual + quaternion layernorm (comp = wave) ----
  const float g0 = gamma[colQ + (t & 15)];  // placeholder to keep loads near
  (void)g0;
  float xv[2][8][4];
#pragma unroll
  for (int st = 0; st < 2; ++st)
#pragma unroll
    for (int f = 0; f < 8; ++f) {
      const int col = colQ + f * 16 + l16;
      const float ubv = ub[col];
#pragma unroll
      for (int rg = 0; rg < 4; ++rg) {
        const size_t row = R0 + st * 16 + g * 4 + rg;
        xv[st][f][rg] = acc[st][f][rg] + ubv + q[row * D_ + col];
      }
    }
#pragma unroll
  for (int st = 0; st < 2; ++st)
#pragma unroll
    for (int rg = 0; rg < 4; ++rg) {
      float s = 0.f;
#pragma unroll
      for (int f = 0; f < 8; ++f) s += xv[st][f][rg];
      s += __shfl_xor(s, 1); s += __shfl_xor(s, 2);
      s += __shfl_xor(s, 4); s += __shfl_xor(s, 8);
      const float mean = s * 0.0078125f;
      float sq = 0.f;
#pragma unroll
      for (int f = 0; f < 8; ++f) {
        const float d = xv[st][f][rg] - mean; sq += d * d;
      }
      sq += __shfl_xor(sq, 1); sq += __shfl_xor(sq, 2);
      sq += __shfl_xor(sq, 4); sq += __shfl_xor(sq, 8);
      const float rstd = rsqrtf(sq * 0.0078125f + 1e-5f);
      const size_t row = R0 + st * 16 + g * 4 + rg;
#pragma unroll
      for (int f = 0; f < 8; ++f) {
        const int col = colQ + f * 16 + l16;
        const float xn = (xv[st][f][rg] - mean) * rstd;
        out_q[row * D_ + col] = xn * gamma[col] + beta[col];
      }
    }
}

extern "C" void kernel_launch(void* const* d_in, const int* in_sizes, int n_in,
                              void* d_out, int out_size, void* d_ws, size_t ws_size,
                              hipStream_t stream) {
  const float* q     = (const float*)d_in[0];
  const int*   aidx  = (const int*)d_in[1];
  const float* aw    = (const float*)d_in[2];
  const float* mask  = (const float*)d_in[3];
  const float* pw    = (const float*)d_in[4];
  const float* pb    = (const float*)d_in[5];
  const float* uw    = (const float*)d_in[6];
  const float* ub    = (const float*)d_in[7];
  const float* gamma = (const float*)d_in[8];
  const float* beta  = (const float*)d_in[9];

  char* ws = (char*)d_ws;
  float* proto_raw = (float*)ws;                               // 1 MB
  float* wsum      = (float*)(ws + (1 << 20));                 // 2 KB (pad 4KB)
  float* proto_t   = (float*)(ws + (1 << 20) + 4096);          // 1 MB
  u16*   wexp      = (u16*)(ws + 2 * (1 << 20) + 4096);        // 512 KB
  u16*   pwexp     = (u16*)(ws + 2 * (1 << 20) + 4096 + (512 << 10)); // 512 KB

  float* out_q = (float*)d_out;                                // (B,N,D) f32
  float* out_proto = out_q + (size_t)B_ * N_ * D_;             // (B,K,D) f32

  hipMemsetAsync(proto_raw, 0, 1 << 20, stream);
  k_wexp_bf<<<1024, 256, 0, stream>>>(uw, wexp);
  k_wexp_bf<<<1024, 256, 0, stream>>>(pw, pwexp);
  k_wsum<<<8, 256, 0, stream>>>(aidx, aw, mask, wsum);
  k_scatter<<<dim3(16, 4, 8), 128, 0, stream>>>(q, aidx, aw, mask, proto_raw);
  k_proto_mfma<<<16, 256, 0, stream>>>(proto_raw, wsum, pwexp, pb, proto_t, out_proto);
  k_main3<<<1024, 256, 0, stream>>>(q, aidx, aw, proto_t, wexp, ub, gamma, beta, out_q);
}

// Round 6
// 195.033 us; speedup vs baseline: 2.5973x; 1.1224x over previous
//
#include <hip/hip_runtime.h>
#include <hip/hip_bf16.h>

#define B_ 8
#define N_ 4096
#define D_ 512
#define K_ 64
#define QD_ 128

typedef float f32x4 __attribute__((ext_vector_type(4)));
typedef short short8 __attribute__((ext_vector_type(8)));
typedef unsigned short u16;
typedef unsigned int u32;

__device__ __forceinline__ u16 f2bf(float f) {
  u32 u = __float_as_uint(f);
  return (u16)((u + 0x7fffu + ((u >> 16) & 1u)) >> 16);
}

__device__ __forceinline__ void load8f(const float* p, float* r) {
  float4 a = *(const float4*)(p);
  float4 b = *(const float4*)(p + 4);
  r[0] = a.x; r[1] = a.y; r[2] = a.z; r[3] = a.w;
  r[4] = b.x; r[5] = b.y; r[6] = b.z; r[7] = b.w;
}

// ---------------------------------------------------------------------------
// K0: expand BOTH quaternion weight sets into dense bf16 W[o][v] (one launch).
// gid < 2^18 -> upd_w -> wexp ; else proto_w -> pwexp.
// ---------------------------------------------------------------------------
__global__ __launch_bounds__(256) void k_wexp2(
    const float* __restrict__ uw, const float* __restrict__ pw,
    u16* __restrict__ wexp, u16* __restrict__ pwexp) {
  const int gid = blockIdx.x * 256 + threadIdx.x;
  const int sel = gid >> 18;
  const int idx = gid & ((1 << 18) - 1);
  const int o = idx >> 9, v = idx & 511;
  const int u = o >> 7, a = o & 127, c = v >> 7, bb = v & 127;
  const int   matT[4][4] = {{0,1,2,3},{1,0,3,2},{2,3,0,1},{3,2,1,0}};
  const float sgnT[4][4] = {{1.f,-1.f,-1.f,-1.f},{1.f,1.f,-1.f,1.f},
                            {1.f,1.f,1.f,-1.f},{1.f,-1.f,1.f,1.f}};
  const float* w4 = sel ? pw : uw;
  u16* dst = sel ? pwexp : wexp;
  dst[idx] = f2bf(sgnT[u][c] * w4[matT[u][c] * QD_ * QD_ + a * QD_ + bb]);
}

// ---------------------------------------------------------------------------
// K1: segment-sum scatter + fused weight-sum. grid (32, 4, 8) x 128.
// Thread t owns column d = dq*128 + t of all 64 bins -> race-free LDS adds.
// Row loop unrolled x4 with hoisted loads to hide global latency.
// wsum built by lanes t<3 via LDS atomics in the dq==0 slice.
// ---------------------------------------------------------------------------
__global__ __launch_bounds__(128) void k_scatter(
    const float* __restrict__ q, const int* __restrict__ aidx,
    const float* __restrict__ aw, const float* __restrict__ mask,
    float* __restrict__ proto_raw, float* __restrict__ wsum) {
  __shared__ float acc[K_ * 128];
  __shared__ float wsh[K_];
  const int t = threadIdx.x;
  const int chunk = blockIdx.x;   // 0..31
  const int dq = blockIdx.y;      // 0..3
  const int b = blockIdx.z;       // 0..7
  for (int i = t; i < K_ * 128; i += 128) acc[i] = 0.f;
  if (dq == 0 && t < K_) wsh[t] = 0.f;
  __syncthreads();
  const int rows = N_ / 32;  // 128
  const int n0 = chunk * rows;
  for (int r = 0; r < rows; r += 4) {
    float qv[4], ww[4][3];
    int kk[4][3];
#pragma unroll
    for (int rr = 0; rr < 4; ++rr) {
      const size_t gr = (size_t)b * N_ + (n0 + r + rr);
      qv[rr] = q[gr * D_ + dq * 128 + t];
      const float mk = mask[gr];
      const int* ip = aidx + gr * 3;
      const float* wp = aw + gr * 3;
#pragma unroll
      for (int j = 0; j < 3; ++j) { kk[rr][j] = ip[j]; ww[rr][j] = wp[j] * mk; }
    }
#pragma unroll
    for (int rr = 0; rr < 4; ++rr)
#pragma unroll
      for (int j = 0; j < 3; ++j)
        acc[kk[rr][j] * 128 + t] += qv[rr] * ww[rr][j];
    if (dq == 0 && t < 3) {
#pragma unroll
      for (int rr = 0; rr < 4; ++rr) atomicAdd(&wsh[kk[rr][t]], ww[rr][t]);
    }
  }
  __syncthreads();
  for (int i = t; i < K_ * 128; i += 128) {
    const int k = i >> 7;  // i % 128 == t
    atomicAdd(&proto_raw[(size_t)(b * K_ + k) * D_ + dq * 128 + t], acc[i]);
  }
  if (dq == 0 && t < K_) atomicAdd(&wsum[b * K_ + t], wsh[t]);
}

// ---------------------------------------------------------------------------
// K2: proto normalize + quaternion_linear via bf16 MFMA.
// 16 blocks x 256 threads. 32 proto rows/block, wave w owns cols [w*128,..).
// ---------------------------------------------------------------------------
__global__ __launch_bounds__(256) void k_proto_mfma(
    const float* __restrict__ proto_raw, const float* __restrict__ wsum,
    const u16* __restrict__ pwexp, const float* __restrict__ pb,
    float* __restrict__ proto_t, float* __restrict__ out_proto) {
  __shared__ __align__(16) u16 msgL[32 * 512];
  __shared__ float invs[32];
  const int t = threadIdx.x;
  const size_t R0 = (size_t)blockIdx.x * 32;
  if (t < 32) invs[t] = 1.f / (wsum[R0 + t] + 1e-6f);
  __syncthreads();

  {
    const int s = t & 15, rr = t >> 4;
#pragma unroll
    for (int pass = 0; pass < 2; ++pass) {
      const int row = pass * 16 + rr;
      const float iv = invs[row];
      const float* base = proto_raw + (R0 + row) * D_;
      const int swz = (row & 7) << 4;
#pragma unroll
      for (int u = 0; u < 4; ++u) {
        float m[8];
        load8f(base + u * 128 + s * 8, m);
        uint4 val;
        val.x = (u32)f2bf(m[0]*iv) | ((u32)f2bf(m[1]*iv) << 16);
        val.y = (u32)f2bf(m[2]*iv) | ((u32)f2bf(m[3]*iv) << 16);
        val.z = (u32)f2bf(m[4]*iv) | ((u32)f2bf(m[5]*iv) << 16);
        val.w = (u32)f2bf(m[6]*iv) | ((u32)f2bf(m[7]*iv) << 16);
        const int byte = (row * 1024 + u * 256 + s * 16) ^ swz;
        *(uint4*)((char*)msgL + byte) = val;
      }
    }
  }
  __syncthreads();

  const int lane = t & 63, wv = t >> 6;
  const int g = lane >> 4, l16 = lane & 15;
  const int colQ = wv * 128;
  f32x4 acc[2][8];
#pragma unroll
  for (int st = 0; st < 2; ++st)
#pragma unroll
    for (int f = 0; f < 8; ++f) { f32x4 z = {0.f,0.f,0.f,0.f}; acc[st][f] = z; }
#pragma unroll 4
  for (int ks = 0; ks < 16; ++ks) {
    short8 bfr[8];
#pragma unroll
    for (int f = 0; f < 8; ++f)
      bfr[f] = *(const short8*)(pwexp + (size_t)(colQ + f * 16 + l16) * D_ + ks * 32 + g * 8);
#pragma unroll
    for (int st = 0; st < 2; ++st) {
      const int arow = st * 16 + l16;
      const short8 a = *(const short8*)((const char*)msgL +
          ((arow * 1024 + ks * 64 + g * 16) ^ ((arow & 7) << 4)));
#pragma unroll
      for (int f = 0; f < 8; ++f)
        acc[st][f] = __builtin_amdgcn_mfma_f32_16x16x32_bf16(a, bfr[f], acc[st][f], 0, 0, 0);
    }
  }

#pragma unroll
  for (int st = 0; st < 2; ++st)
#pragma unroll
    for (int f = 0; f < 8; ++f) {
      const int col = colQ + f * 16 + l16;
      const float pbv = pb[col];
#pragma unroll
      for (int rg = 0; rg < 4; ++rg) {
        const size_t row = R0 + st * 16 + g * 4 + rg;
        const float v = acc[st][f][rg] + pbv;
        proto_t[row * D_ + col] = v;
        out_proto[row * D_ + col] = v;
      }
    }
}

// ---------------------------------------------------------------------------
// K3: fused routing + hamilton + upd linear (bf16 MFMA) + residual + quat-LN.
// 512 blocks x 512 threads (8 waves); 64 rows/block.
// Wave wid = (r2 = wid>>2 row strip of 32, c4 = wid&3 quaternion component).
// ---------------------------------------------------------------------------
__global__ __launch_bounds__(512, 4) void k_main4(
    const float* __restrict__ q, const int* __restrict__ aidx,
    const float* __restrict__ aw, const float* __restrict__ proto_t,
    const u16* __restrict__ wexp, const float* __restrict__ ub,
    const float* __restrict__ gamma, const float* __restrict__ beta,
    float* __restrict__ out_q) {
  __shared__ __align__(16) u16 msgL[64 * 512];  // 64 KB, XOR-swizzled
  const int t = threadIdx.x;
  const size_t R0 = (size_t)blockIdx.x * 64;

  // ---- stage A: Hamilton-weighted msg rows -> bf16 swizzled LDS ----
  {
    const int s = t & 15, rowHalf = t >> 4;  // rowHalf 0..31
    // hoist all index/weight loads (independent of q/proto loads)
    int kks[2][3]; float wws[2][3];
#pragma unroll
    for (int p = 0; p < 2; ++p) {
      const size_t gr = R0 + p * 32 + rowHalf;
      const int* ip = aidx + gr * 3;
      const float* wp = aw + gr * 3;
#pragma unroll
      for (int j = 0; j < 3; ++j) { kks[p][j] = ip[j]; wws[p][j] = wp[j]; }
    }
#pragma unroll
    for (int p = 0; p < 2; ++p) {
      const int row = p * 32 + rowHalf;
      const size_t gr = R0 + row;
      const int b = (int)(gr >> 12);
      const float* qp = q + gr * D_ + s * 8;
      float qr_[8], qi_[8], qj_[8], qk_[8];
      load8f(qp, qr_); load8f(qp + 128, qi_);
      load8f(qp + 256, qj_); load8f(qp + 384, qk_);
      float mr[8], mi[8], mj[8], mk[8];
#pragma unroll
      for (int e = 0; e < 8; ++e) { mr[e] = mi[e] = mj[e] = mk[e] = 0.f; }
#pragma unroll
      for (int j = 0; j < 3; ++j) {
        const float w = wws[p][j];
        const float* pp = proto_t + (size_t)(b * K_ + kks[p][j]) * D_ + s * 8;
        float pr[8], pi[8], pj[8], pk[8];
        load8f(pp, pr); load8f(pp + 128, pi);
        load8f(pp + 256, pj); load8f(pp + 384, pk);
#pragma unroll
        for (int e = 0; e < 8; ++e) {
          mr[e] += w * (qr_[e]*pr[e] - qi_[e]*pi[e] - qj_[e]*pj[e] - qk_[e]*pk[e]);
          mi[e] += w * (qr_[e]*pi[e] + qi_[e]*pr[e] + qj_[e]*pk[e] - qk_[e]*pj[e]);
          mj[e] += w * (qr_[e]*pj[e] - qi_[e]*pk[e] + qj_[e]*pr[e] + qk_[e]*pi[e]);
          mk[e] += w * (qr_[e]*pk[e] + qi_[e]*pj[e] - qj_[e]*pi[e] + qk_[e]*pr[e]);
        }
      }
      const int swz = (row & 7) << 4;
      const float* srcs[4] = {mr, mi, mj, mk};
#pragma unroll
      for (int u = 0; u < 4; ++u) {
        const float* m = srcs[u];
        uint4 val;
        val.x = (u32)f2bf(m[0]) | ((u32)f2bf(m[1]) << 16);
        val.y = (u32)f2bf(m[2]) | ((u32)f2bf(m[3]) << 16);
        val.z = (u32)f2bf(m[4]) | ((u32)f2bf(m[5]) << 16);
        val.w = (u32)f2bf(m[6]) | ((u32)f2bf(m[7]) << 16);
        const int byte = (row * 1024 + u * 256 + s * 16) ^ swz;
        *(uint4*)((char*)msgL + byte) = val;
      }
    }
  }
  __syncthreads();

  // ---- stage B: GEMM 64x512x512 via mfma_f32_16x16x32_bf16 ----
  const int lane = t & 63, wid = t >> 6;
  const int g = lane >> 4, l16 = lane & 15;
  const int c4 = wid & 3, r2 = wid >> 2;
  const int colQ = c4 * 128;
  f32x4 acc[2][8];
#pragma unroll
  for (int st = 0; st < 2; ++st)
#pragma unroll
    for (int f = 0; f < 8; ++f) { f32x4 z = {0.f,0.f,0.f,0.f}; acc[st][f] = z; }
#pragma unroll 4
  for (int ks = 0; ks < 16; ++ks) {
    short8 bfr[8];
#pragma unroll
    for (int f = 0; f < 8; ++f)
      bfr[f] = *(const short8*)(wexp + (size_t)(colQ + f * 16 + l16) * D_ + ks * 32 + g * 8);
#pragma unroll
    for (int st = 0; st < 2; ++st) {
      const int arow = r2 * 32 + st * 16 + l16;
      const short8 a = *(const short8*)((const char*)msgL +
          ((arow * 1024 + ks * 64 + g * 16) ^ ((arow & 7) << 4)));
#pragma unroll
      for (int f = 0; f < 8; ++f)
        acc[st][f] = __builtin_amdgcn_mfma_f32_16x16x32_bf16(a, bfr[f], acc[st][f], 0, 0, 0);
    }
  }

  // ---- epilogue: bias + residual + quaternion layernorm (comp = c4) ----
  float xv[2][8][4];
#pragma unroll
  for (int st = 0; st < 2; ++st)
#pragma unroll
    for (int f = 0; f < 8; ++f) {
      const int col = colQ + f * 16 + l16;
      const float ubv = ub[col];
#pragma unroll
      for (int rg = 0; rg < 4; ++rg) {
        const size_t row = R0 + r2 * 32 + st * 16 + g * 4 + rg;
        xv[st][f][rg] = acc[st][f][rg] + ubv + q[row * D_ + col];
      }
    }
#pragma unroll
  for (int st = 0; st < 2; ++st)
#pragma unroll
    for (int rg = 0; rg < 4; ++rg) {
      float s = 0.f;
#pragma unroll
      for (int f = 0; f < 8; ++f) s += xv[st][f][rg];
      s += __shfl_xor(s, 1); s += __shfl_xor(s, 2);
      s += __shfl_xor(s, 4); s += __shfl_xor(s, 8);
      const float mean = s * 0.0078125f;
      float sq = 0.f;
#pragma unroll
      for (int f = 0; f < 8; ++f) {
        const float d = xv[st][f][rg] - mean; sq += d * d;
      }
      sq += __shfl_xor(sq, 1); sq += __shfl_xor(sq, 2);
      sq += __shfl_xor(sq, 4); sq += __shfl_xor(sq, 8);
      const float rstd = rsqrtf(sq * 0.0078125f + 1e-5f);
      const size_t row = R0 + r2 * 32 + st * 16 + g * 4 + rg;
#pragma unroll
      for (int f = 0; f < 8; ++f) {
        const int col = colQ + f * 16 + l16;
        const float xn = (xv[st][f][rg] - mean) * rstd;
        out_q[row * D_ + col] = xn * gamma[col] + beta[col];
      }
    }
}

extern "C" void kernel_launch(void* const* d_in, const int* in_sizes, int n_in,
                              void* d_out, int out_size, void* d_ws, size_t ws_size,
                              hipStream_t stream) {
  const float* q     = (const float*)d_in[0];
  const int*   aidx  = (const int*)d_in[1];
  const float* aw    = (const float*)d_in[2];
  const float* mask  = (const float*)d_in[3];
  const float* pw    = (const float*)d_in[4];
  const float* pb    = (const float*)d_in[5];
  const float* uw    = (const float*)d_in[6];
  const float* ub    = (const float*)d_in[7];
  const float* gamma = (const float*)d_in[8];
  const float* beta  = (const float*)d_in[9];

  char* ws = (char*)d_ws;
  float* proto_raw = (float*)ws;                               // 1 MB
  float* wsum      = (float*)(ws + (1 << 20));                 // 2 KB (pad 4KB)
  float* proto_t   = (float*)(ws + (1 << 20) + 4096);          // 1 MB
  u16*   wexp      = (u16*)(ws + 2 * (1 << 20) + 4096);        // 512 KB
  u16*   pwexp     = (u16*)(ws + 2 * (1 << 20) + 4096 + (512 << 10)); // 512 KB

  float* out_q = (float*)d_out;                                // (B,N,D) f32
  float* out_proto = out_q + (size_t)B_ * N_ * D_;             // (B,K,D) f32

  hipMemsetAsync(proto_raw, 0, (1 << 20) + 4096, stream);      // proto_raw + wsum
  k_wexp2<<<2048, 256, 0, stream>>>(uw, pw, wexp, pwexp);
  k_scatter<<<dim3(32, 4, 8), 128, 0, stream>>>(q, aidx, aw, mask, proto_raw, wsum);
  k_proto_mfma<<<16, 256, 0, stream>>>(proto_raw, wsum, pwexp, pb, proto_t, out_proto);
  k_main4<<<512, 512, 0, stream>>>(q, aidx, aw, proto_t, wexp, ub, gamma, beta, out_q);
}

// Round 7
// 153.165 us; speedup vs baseline: 3.3073x; 1.2733x over previous
//
#include <hip/hip_runtime.h>
#include <hip/hip_bf16.h>

#define B_ 8
#define N_ 4096
#define D_ 512
#define K_ 64
#define QD_ 128

typedef float f32x4 __attribute__((ext_vector_type(4)));
typedef short short8 __attribute__((ext_vector_type(8)));
typedef unsigned short u16;
typedef unsigned int u32;

__device__ __forceinline__ u16 f2bf(float f) {
  u32 u = __float_as_uint(f);
  return (u16)((u + 0x7fffu + ((u >> 16) & 1u)) >> 16);
}

__device__ __forceinline__ void load8f(const float* p, float* r) {
  float4 a = *(const float4*)(p);
  float4 b = *(const float4*)(p + 4);
  r[0] = a.x; r[1] = a.y; r[2] = a.z; r[3] = a.w;
  r[4] = b.x; r[5] = b.y; r[6] = b.z; r[7] = b.w;
}

// ---------------------------------------------------------------------------
// K0: expand BOTH quaternion weight sets into *fragment-ordered* bf16 buffers.
// Layout: wf[(((cf*16)+ks)*64 + lane)*8 + e] = W[col][v], where
//   cf = c4*8+f in [0,32), col = (cf>>3)*128 + (cf&7)*16 + (lane&15),
//   v  = ks*32 + (lane>>4)*8 + e.
// So each wave's (c4,f,ks) B-fragment load is one contiguous 1KB chunk.
// ---------------------------------------------------------------------------
__global__ __launch_bounds__(256) void k_wexp_frag(
    const float* __restrict__ uw, const float* __restrict__ pw,
    u16* __restrict__ uwf, u16* __restrict__ pwf) {
  const int gid = blockIdx.x * 256 + threadIdx.x;  // < 2 * 2^18
  const int sel = gid >> 18;
  const int idx = gid & ((1 << 18) - 1);
  const int e = idx & 7;
  const int lane = (idx >> 3) & 63;
  const int ks = (idx >> 9) & 15;
  const int cf = idx >> 13;  // 0..31
  const int col = (cf >> 3) * 128 + (cf & 7) * 16 + (lane & 15);
  const int v = ks * 32 + (lane >> 4) * 8 + e;
  const int u = col >> 7, a = col & 127, c = v >> 7, bb = v & 127;
  const int   matT[4][4] = {{0,1,2,3},{1,0,3,2},{2,3,0,1},{3,2,1,0}};
  const float sgnT[4][4] = {{1.f,-1.f,-1.f,-1.f},{1.f,1.f,-1.f,1.f},
                            {1.f,1.f,1.f,-1.f},{1.f,-1.f,1.f,1.f}};
  const float* w4 = sel ? pw : uw;
  u16* dst = sel ? pwf : uwf;
  dst[idx] = f2bf(sgnT[u][c] * w4[matT[u][c] * QD_ * QD_ + a * QD_ + bb]);
}

// ---------------------------------------------------------------------------
// K1: segment-sum scatter + fused weight-sum. grid (32, 4, 8) x 128.
// Thread t owns column d = dq*128 + t of all 64 bins -> race-free LDS adds.
// ---------------------------------------------------------------------------
__global__ __launch_bounds__(128) void k_scatter(
    const float* __restrict__ q, const int* __restrict__ aidx,
    const float* __restrict__ aw, const float* __restrict__ mask,
    float* __restrict__ proto_raw, float* __restrict__ wsum) {
  __shared__ float acc[K_ * 128];
  __shared__ float wsh[K_];
  const int t = threadIdx.x;
  const int chunk = blockIdx.x;   // 0..31
  const int dq = blockIdx.y;      // 0..3
  const int b = blockIdx.z;       // 0..7
  for (int i = t; i < K_ * 128; i += 128) acc[i] = 0.f;
  if (dq == 0 && t < K_) wsh[t] = 0.f;
  __syncthreads();
  const int rows = N_ / 32;  // 128
  const int n0 = chunk * rows;
  for (int r = 0; r < rows; r += 4) {
    float qv[4], ww[4][3];
    int kk[4][3];
#pragma unroll
    for (int rr = 0; rr < 4; ++rr) {
      const size_t gr = (size_t)b * N_ + (n0 + r + rr);
      qv[rr] = q[gr * D_ + dq * 128 + t];
      const float mk = mask[gr];
      const int* ip = aidx + gr * 3;
      const float* wp = aw + gr * 3;
#pragma unroll
      for (int j = 0; j < 3; ++j) { kk[rr][j] = ip[j]; ww[rr][j] = wp[j] * mk; }
    }
#pragma unroll
    for (int rr = 0; rr < 4; ++rr)
#pragma unroll
      for (int j = 0; j < 3; ++j)
        acc[kk[rr][j] * 128 + t] += qv[rr] * ww[rr][j];
    if (dq == 0 && t < 3) {
#pragma unroll
      for (int rr = 0; rr < 4; ++rr) atomicAdd(&wsh[kk[rr][t]], ww[rr][t]);
    }
  }
  __syncthreads();
  for (int i = t; i < K_ * 128; i += 128) {
    const int k = i >> 7;  // i % 128 == t
    atomicAdd(&proto_raw[(size_t)(b * K_ + k) * D_ + dq * 128 + t], acc[i]);
  }
  if (dq == 0 && t < K_) atomicAdd(&wsum[b * K_ + t], wsh[t]);
}

// ---------------------------------------------------------------------------
// K2: proto normalize + quaternion_linear via bf16 MFMA.
// 32 blocks x 256 threads; 16 proto rows/block; wave wv owns cols [wv*128,..).
// ---------------------------------------------------------------------------
__global__ __launch_bounds__(256) void k_proto_mfma(
    const float* __restrict__ proto_raw, const float* __restrict__ wsum,
    const u16* __restrict__ pwf, const float* __restrict__ pb,
    float* __restrict__ proto_t, float* __restrict__ out_proto) {
  __shared__ __align__(16) u16 msgL[16 * 512];
  __shared__ float invs[16];
  const int t = threadIdx.x;
  const size_t R0 = (size_t)blockIdx.x * 16;
  if (t < 16) invs[t] = 1.f / (wsum[R0 + t] + 1e-6f);
  __syncthreads();

  {
    const int s = t & 15, row = t >> 4;  // row 0..15
    const float iv = invs[row];
    const float* base = proto_raw + (R0 + row) * D_;
    const int swz = (row & 7) << 4;
#pragma unroll
    for (int u = 0; u < 4; ++u) {
      float m[8];
      load8f(base + u * 128 + s * 8, m);
      uint4 val;
      val.x = (u32)f2bf(m[0]*iv) | ((u32)f2bf(m[1]*iv) << 16);
      val.y = (u32)f2bf(m[2]*iv) | ((u32)f2bf(m[3]*iv) << 16);
      val.z = (u32)f2bf(m[4]*iv) | ((u32)f2bf(m[5]*iv) << 16);
      val.w = (u32)f2bf(m[6]*iv) | ((u32)f2bf(m[7]*iv) << 16);
      const int byte = (row * 1024 + u * 256 + s * 16) ^ swz;
      *(uint4*)((char*)msgL + byte) = val;
    }
  }
  __syncthreads();

  const int lane = t & 63, wv = t >> 6;
  const int g = lane >> 4, l16 = lane & 15;
  f32x4 acc[8];
#pragma unroll
  for (int f = 0; f < 8; ++f) { f32x4 z = {0.f,0.f,0.f,0.f}; acc[f] = z; }
#pragma unroll 4
  for (int ks = 0; ks < 16; ++ks) {
    const int arow = l16;
    const short8 a = *(const short8*)((const char*)msgL +
        ((arow * 1024 + ks * 64 + g * 16) ^ ((arow & 7) << 4)));
#pragma unroll
    for (int f = 0; f < 8; ++f) {
      const short8 bv = *(const short8*)(pwf +
          ((size_t)((wv * 8 + f) * 16 + ks) * 64 + lane) * 8);
      acc[f] = __builtin_amdgcn_mfma_f32_16x16x32_bf16(a, bv, acc[f], 0, 0, 0);
    }
  }

#pragma unroll
  for (int f = 0; f < 8; ++f) {
    const int col = wv * 128 + f * 16 + l16;
    const float pbv = pb[col];
#pragma unroll
    for (int rg = 0; rg < 4; ++rg) {
      const size_t row = R0 + g * 4 + rg;
      const float v = acc[f][rg] + pbv;
      proto_t[row * D_ + col] = v;
      out_proto[row * D_ + col] = v;
    }
  }
}

// ---------------------------------------------------------------------------
// K3: fused routing + hamilton + upd linear (bf16 MFMA) + residual + quat-LN.
// 512 blocks x 512 threads (8 waves); 64 rows/block.
// Wave wid = (r2 = wid>>2 row strip of 32, c4 = wid&3 quaternion component).
// __launch_bounds__(512,2): 2nd arg = min BLOCKS/CU (CUDA semantics) -> 128
// VGPR cap; epilogue reuses acc in place so demand fits without spills.
// ---------------------------------------------------------------------------
__global__ __launch_bounds__(512, 2) void k_main5(
    const float* __restrict__ q, const int* __restrict__ aidx,
    const float* __restrict__ aw, const float* __restrict__ proto_t,
    const u16* __restrict__ uwf, const float* __restrict__ ub,
    const float* __restrict__ gamma, const float* __restrict__ beta,
    float* __restrict__ out_q) {
  __shared__ __align__(16) u16 msgL[64 * 512];  // 64 KB, XOR-swizzled
  const int t = threadIdx.x;
  const size_t R0 = (size_t)blockIdx.x * 64;

  // ---- stage A: Hamilton-weighted msg rows -> bf16 swizzled LDS ----
  {
    const int s = t & 15, rowHalf = t >> 4;  // rowHalf 0..31
    int kks[2][3]; float wws[2][3];
#pragma unroll
    for (int p = 0; p < 2; ++p) {
      const size_t gr = R0 + p * 32 + rowHalf;
      const int* ip = aidx + gr * 3;
      const float* wp = aw + gr * 3;
#pragma unroll
      for (int j = 0; j < 3; ++j) { kks[p][j] = ip[j]; wws[p][j] = wp[j]; }
    }
#pragma unroll
    for (int p = 0; p < 2; ++p) {
      const int row = p * 32 + rowHalf;
      const size_t gr = R0 + row;
      const int b = (int)(gr >> 12);
      const float* qp = q + gr * D_ + s * 8;
      float qr_[8], qi_[8], qj_[8], qk_[8];
      load8f(qp, qr_); load8f(qp + 128, qi_);
      load8f(qp + 256, qj_); load8f(qp + 384, qk_);
      float mr[8], mi[8], mj[8], mk[8];
#pragma unroll
      for (int e = 0; e < 8; ++e) { mr[e] = mi[e] = mj[e] = mk[e] = 0.f; }
#pragma unroll
      for (int j = 0; j < 3; ++j) {
        const float w = wws[p][j];
        const float* pp = proto_t + (size_t)(b * K_ + kks[p][j]) * D_ + s * 8;
        float pr[8], pi[8], pj[8], pk[8];
        load8f(pp, pr); load8f(pp + 128, pi);
        load8f(pp + 256, pj); load8f(pp + 384, pk);
#pragma unroll
        for (int e = 0; e < 8; ++e) {
          mr[e] += w * (qr_[e]*pr[e] - qi_[e]*pi[e] - qj_[e]*pj[e] - qk_[e]*pk[e]);
          mi[e] += w * (qr_[e]*pi[e] + qi_[e]*pr[e] + qj_[e]*pk[e] - qk_[e]*pj[e]);
          mj[e] += w * (qr_[e]*pj[e] - qi_[e]*pk[e] + qj_[e]*pr[e] + qk_[e]*pi[e]);
          mk[e] += w * (qr_[e]*pk[e] + qi_[e]*pj[e] - qj_[e]*pi[e] + qk_[e]*pr[e]);
        }
      }
      const int swz = (row & 7) << 4;
      const float* srcs[4] = {mr, mi, mj, mk};
#pragma unroll
      for (int u = 0; u < 4; ++u) {
        const float* m = srcs[u];
        uint4 val;
        val.x = (u32)f2bf(m[0]) | ((u32)f2bf(m[1]) << 16);
        val.y = (u32)f2bf(m[2]) | ((u32)f2bf(m[3]) << 16);
        val.z = (u32)f2bf(m[4]) | ((u32)f2bf(m[5]) << 16);
        val.w = (u32)f2bf(m[6]) | ((u32)f2bf(m[7]) << 16);
        const int byte = (row * 1024 + u * 256 + s * 16) ^ swz;
        *(uint4*)((char*)msgL + byte) = val;
      }
    }
  }
  __syncthreads();

  // ---- stage B: GEMM 64x512x512 via mfma_f32_16x16x32_bf16 ----
  const int lane = t & 63, wid = t >> 6;
  const int g = lane >> 4, l16 = lane & 15;
  const int c4 = wid & 3, r2 = wid >> 2;
  f32x4 acc[2][8];
#pragma unroll
  for (int st = 0; st < 2; ++st)
#pragma unroll
    for (int f = 0; f < 8; ++f) { f32x4 z = {0.f,0.f,0.f,0.f}; acc[st][f] = z; }
#pragma unroll 2
  for (int ks = 0; ks < 16; ++ks) {
    short8 bfr[8];
#pragma unroll
    for (int f = 0; f < 8; ++f)
      bfr[f] = *(const short8*)(uwf +
          ((size_t)((c4 * 8 + f) * 16 + ks) * 64 + lane) * 8);
#pragma unroll
    for (int st = 0; st < 2; ++st) {
      const int arow = r2 * 32 + st * 16 + l16;
      const short8 a = *(const short8*)((const char*)msgL +
          ((arow * 1024 + ks * 64 + g * 16) ^ ((arow & 7) << 4)));
#pragma unroll
      for (int f = 0; f < 8; ++f)
        acc[st][f] = __builtin_amdgcn_mfma_f32_16x16x32_bf16(a, bfr[f], acc[st][f], 0, 0, 0);
    }
  }

  // ---- epilogue: bias + residual folded into acc, then quat-LN ----
  const int colQ = c4 * 128;
#pragma unroll
  for (int st = 0; st < 2; ++st)
#pragma unroll
    for (int f = 0; f < 8; ++f) {
      const int col = colQ + f * 16 + l16;
      const float ubv = ub[col];
#pragma unroll
      for (int rg = 0; rg < 4; ++rg) {
        const size_t row = R0 + r2 * 32 + st * 16 + g * 4 + rg;
        acc[st][f][rg] += ubv + q[row * D_ + col];
      }
    }
#pragma unroll
  for (int st = 0; st < 2; ++st)
#pragma unroll
    for (int rg = 0; rg < 4; ++rg) {
      float s = 0.f;
#pragma unroll
      for (int f = 0; f < 8; ++f) s += acc[st][f][rg];
      s += __shfl_xor(s, 1); s += __shfl_xor(s, 2);
      s += __shfl_xor(s, 4); s += __shfl_xor(s, 8);
      const float mean = s * 0.0078125f;
      float sq = 0.f;
#pragma unroll
      for (int f = 0; f < 8; ++f) {
        const float d = acc[st][f][rg] - mean; sq += d * d;
      }
      sq += __shfl_xor(sq, 1); sq += __shfl_xor(sq, 2);
      sq += __shfl_xor(sq, 4); sq += __shfl_xor(sq, 8);
      const float rstd = rsqrtf(sq * 0.0078125f + 1e-5f);
      const size_t row = R0 + r2 * 32 + st * 16 + g * 4 + rg;
#pragma unroll
      for (int f = 0; f < 8; ++f) {
        const int col = colQ + f * 16 + l16;
        const float xn = (acc[st][f][rg] - mean) * rstd;
        out_q[row * D_ + col] = xn * gamma[col] + beta[col];
      }
    }
}

extern "C" void kernel_launch(void* const* d_in, const int* in_sizes, int n_in,
                              void* d_out, int out_size, void* d_ws, size_t ws_size,
                              hipStream_t stream) {
  const float* q     = (const float*)d_in[0];
  const int*   aidx  = (const int*)d_in[1];
  const float* aw    = (const float*)d_in[2];
  const float* mask  = (const float*)d_in[3];
  const float* pw    = (const float*)d_in[4];
  const float* pb    = (const float*)d_in[5];
  const float* uw    = (const float*)d_in[6];
  const float* ub    = (const float*)d_in[7];
  const float* gamma = (const float*)d_in[8];
  const float* beta  = (const float*)d_in[9];

  char* ws = (char*)d_ws;
  float* proto_raw = (float*)ws;                               // 1 MB
  float* wsum      = (float*)(ws + (1 << 20));                 // 2 KB (pad 4KB)
  float* proto_t   = (float*)(ws + (1 << 20) + 4096);          // 1 MB
  u16*   uwf       = (u16*)(ws + 2 * (1 << 20) + 4096);        // 512 KB
  u16*   pwf       = (u16*)(ws + 2 * (1 << 20) + 4096 + (512 << 10)); // 512 KB

  float* out_q = (float*)d_out;                                // (B,N,D) f32
  float* out_proto = out_q + (size_t)B_ * N_ * D_;             // (B,K,D) f32

  hipMemsetAsync(proto_raw, 0, (1 << 20) + 4096, stream);      // proto_raw + wsum
  k_wexp_frag<<<2048, 256, 0, stream>>>(uw, pw, uwf, pwf);
  k_scatter<<<dim3(32, 4, 8), 128, 0, stream>>>(q, aidx, aw, mask, proto_raw, wsum);
  k_proto_mfma<<<32, 256, 0, stream>>>(proto_raw, wsum, pwf, pb, proto_t, out_proto);
  k_main5<<<512, 512, 0, stream>>>(q, aidx, aw, proto_t, uwf, ub, gamma, beta, out_q);
}